// Round 1
// baseline (470.438 us; speedup 1.0000x reference)
//
#include <hip/hip_runtime.h>

typedef _Float16 h4 __attribute__((ext_vector_type(4)));
typedef _Float16 h8 __attribute__((ext_vector_type(8)));
typedef float f4 __attribute__((ext_vector_type(4)));

#define MFMA16(a, b, c) __builtin_amdgcn_mfma_f32_16x16x32_f16((a), (b), (c), 0, 0, 0)

static constexpr int TT  = 1024;
static constexpr int BS  = 1024;
static constexpr int LCH = 64;   // chunk length
static constexpr int NCH = 16;   // number of chunks
static constexpr size_t XTOT = (size_t)TT * BS * 128;

// workspace byte offsets
static constexpr size_t WS_WT16 = 0;       // 128x128 f16 : W_eff^T-layout (= S row-major)
static constexpr size_t WS_HF1  = 32768;   // 128x64  f16
static constexpr size_t WS_HF2  = 49152;   // 64x128  f16
static constexpr size_t WS_BW   = 65536;   // 128x64  f16
static constexpr size_t WS_EW   = 81920;   // 128x32  f16
static constexpr size_t WS_WL16 = 90112;   // 128x128 f16 : (W^64) same layout
static constexpr size_t WS_W32A = 122880;  // 128x128 f32 scratch
static constexpr size_t WS_W32B = 188416;  // 128x128 f32 scratch
static constexpr size_t WS_F    = 253952;  // 16*1024*128 f32: chunk-local finals
static constexpr size_t WS_INIT = WS_F + (size_t)16 * 1024 * 128 * 4; // 16*1024*128 f32

// ---------------------------------------------------------------------------
// prep: W_eff (softmax+scale, stored transposed = S row-major) + weight f16 copies
// ---------------------------------------------------------------------------
__global__ void prep_kernel(const float* __restrict__ Aw, const float* __restrict__ As,
                            const float* __restrict__ hf1, const float* __restrict__ hf2,
                            const float* __restrict__ Bw, const float* __restrict__ Ew,
                            char* __restrict__ ws)
{
    const int tid = threadIdx.x;  // 128
    const int bid = blockIdx.x;   // 160
    if (bid < 128) {
        __shared__ float red[128];
        const int n = bid;
        const float a = Aw[n * 128 + tid];
        red[tid] = a;
        __syncthreads();
        for (int s = 64; s > 0; s >>= 1) {
            if (tid < s) red[tid] = fmaxf(red[tid], red[tid + s]);
            __syncthreads();
        }
        const float mx = red[0];
        __syncthreads();
        const float e = expf(a - mx);
        red[tid] = e;
        __syncthreads();
        for (int s = 64; s > 0; s >>= 1) {
            if (tid < s) red[tid] += red[tid + s];
            __syncthreads();
        }
        const float sm  = e / red[0];
        const float asv = As[n * 128 + tid];
        const float sc  = 1.0f - 0.1f * (1.0f / (1.0f + expf(-asv)));
        const float val = sc * sm;   // S[n][tid]
        ((_Float16*)(ws + WS_WT16))[n * 128 + tid] = (_Float16)val;
        ((float*)(ws + WS_W32A))[n * 128 + tid]    = val;
    } else {
        const int b2 = bid - 128;  // 32 blocks
        for (int i = b2 * 128 + tid; i < 8192; i += 32 * 128) {
            ((_Float16*)(ws + WS_HF1))[i] = (_Float16)hf1[i];
            ((_Float16*)(ws + WS_HF2))[i] = (_Float16)hf2[i];
            ((_Float16*)(ws + WS_BW))[i]  = (_Float16)Bw[i];
            if (i < 4096) ((_Float16*)(ws + WS_EW))[i] = (_Float16)Ew[i];
        }
    }
}

// ---------------------------------------------------------------------------
// transposed-layout matrix square: Tout[n][k] = sum_m Tin[m][k]*Tin[n][m]
// (T[a][b] == W[b][a]; this computes W^2 in the same transposed layout)
// ---------------------------------------------------------------------------
__global__ void matsq_kernel(const float* __restrict__ in, float* __restrict__ out)
{
    const int idx = blockIdx.x * 256 + threadIdx.x;  // 64 blocks
    const int n = idx >> 7, k = idx & 127;
    float acc = 0.f;
    for (int m = 0; m < 128; ++m) acc += in[m * 128 + k] * in[n * 128 + m];
    out[idx] = acc;
}

__global__ void conv_kernel(const float* __restrict__ in, char* __restrict__ ws)
{
    const int idx = blockIdx.x * 256 + threadIdx.x;  // 64 blocks -> 16384
    ((_Float16*)(ws + WS_WL16))[idx] = (_Float16)in[idx];
}

// ---------------------------------------------------------------------------
// fused chunk scan. FINAL=false: local scan (zero init), write F_c only.
// FINAL=true: true scan (init from INIT), write X and Y.
// grid: (c * 64 + btile); block 256 = 4 waves; 16 b-rows per block.
// ---------------------------------------------------------------------------
template <bool FINAL>
__global__ __launch_bounds__(256, 2)
void scan_chunk(const float* __restrict__ Mfl, const float* __restrict__ DTi,
                const float* __restrict__ Din, char* __restrict__ ws,
                float* __restrict__ Xout, float* __restrict__ Yout)
{
    const int tid  = threadIdx.x;
    const int lane = tid & 63;
    const int w    = tid >> 6;       // wave 0..3
    const int cl   = lane & 15;      // row of A-frag / col of C-frag
    const int gq   = lane >> 4;      // k-group / row-group
    const int bt   = blockIdx.x & 63;
    const int c    = blockIdx.x >> 6;
    const int b0   = bt * 16;

    const _Float16* Wt16 = (const _Float16*)(ws + WS_WT16);
    const _Float16* Hf1  = (const _Float16*)(ws + WS_HF1);
    const _Float16* Hf2  = (const _Float16*)(ws + WS_HF2);
    const _Float16* Bw16 = (const _Float16*)(ws + WS_BW);
    const _Float16* Ew16 = (const _Float16*)(ws + WS_EW);
    float* Fbuf          = (float*)(ws + WS_F);
    const float* Init    = (const float*)(ws + WS_INIT);

    __shared__ __align__(16) _Float16 xs[2][16 * 128];
    __shared__ __align__(16) _Float16 mds[16 * 64];
    __shared__ __align__(16) _Float16 hs[16 * 128];
    __shared__ __align__(16) _Float16 us[16 * 64];
    __shared__ __align__(16) _Float16 dts[16 * 32];

    // ---- weight B-fragments into registers (stay resident across all steps)
    h8 wtf[2][4], hf1f[2][2], bwf[2][2], ewf[2], hf2f[4];
#pragma unroll
    for (int nt = 0; nt < 2; ++nt) {
        const int ng = w * 32 + nt * 16 + cl;
#pragma unroll
        for (int kk = 0; kk < 4; ++kk)
            wtf[nt][kk] = *(const h8*)&Wt16[ng * 128 + kk * 32 + gq * 8];
#pragma unroll
        for (int kk = 0; kk < 2; ++kk) {
            hf1f[nt][kk] = *(const h8*)&Hf1[ng * 64 + kk * 32 + gq * 8];
            bwf[nt][kk]  = *(const h8*)&Bw16[ng * 64 + kk * 32 + gq * 8];
        }
        ewf[nt] = *(const h8*)&Ew16[ng * 32 + gq * 8];
    }
    {
        const int ng = w * 16 + cl;
#pragma unroll
        for (int kk = 0; kk < 4; ++kk)
            hf2f[kk] = *(const h8*)&Hf2[ng * 128 + kk * 32 + gq * 8];
    }

    // ---- initial state into xs[0] (swizzled row-major [16][128] f16)
    if constexpr (FINAL) {
        const int row = tid >> 4, c8 = tid & 15;
        const float* src = &Init[((size_t)c * BS + b0 + row) * 128 + c8 * 8];
        f4 v0 = *(const f4*)src;
        f4 v1 = *(const f4*)(src + 4);
        h8 hv;
#pragma unroll
        for (int j = 0; j < 4; ++j) { hv[j] = (_Float16)v0[j]; hv[4 + j] = (_Float16)v1[j]; }
        *(h8*)&xs[0][row * 128 + ((c8 ^ row) & 15) * 8] = hv;
    } else {
        h8 z = {};
        *(h8*)&xs[0][tid * 8] = z;
    }

    // ---- input prefetch (1536 f32/step; wave-uniform role split)
    f4 p0, p1;
    const int qrow = (tid & 127) >> 3;
    const int qc4  = (tid & 7) * 4;
    auto loadin = [&](int k) {
        const size_t t  = (size_t)c * LCH + k;
        const size_t rb = (t * BS + b0 + qrow) * 32 + qc4;
        p0 = (tid < 128) ? *(const f4*)&Mfl[rb] : *(const f4*)&DTi[rb];
        if (tid < 128) p1 = *(const f4*)&Din[rb];
    };
    loadin(0);

    int cur = 0;
    for (int k = 0; k < LCH; ++k) {
        // ---- stage current inputs (f32 regs -> f16 LDS, swizzled)
        {
            const int col = (tid < 128) ? qc4 : (32 + qc4);
            h4 hv;
#pragma unroll
            for (int j = 0; j < 4; ++j) hv[j] = (_Float16)p0[j];
            *(h4*)&mds[qrow * 64 + (((col >> 3) ^ (qrow & 7)) * 8) + (col & 7)] = hv;
            if (tid < 128) {
                h4 h2;
#pragma unroll
                for (int j = 0; j < 4; ++j) h2[j] = (_Float16)p1[j];
                *(h4*)&dts[qrow * 32 + (((qc4 >> 3) ^ (qrow & 3)) * 8) + (qc4 & 7)] = h2;
            }
        }
        if (k + 1 < LCH) loadin(k + 1);  // prefetch next step
        __syncthreads();  // B1: md/Dt (+ xs written last iter) visible

        // ---- h = relu(md @ hf1^T), cols [w*32, w*32+32)
        f4 hacc[2] = {};
#pragma unroll
        for (int kk = 0; kk < 2; ++kk) {
            h8 a = *(const h8*)&mds[cl * 64 + (((kk * 4 + gq) ^ (cl & 7)) * 8)];
            hacc[0] = MFMA16(a, hf1f[0][kk], hacc[0]);
            hacc[1] = MFMA16(a, hf1f[1][kk], hacc[1]);
        }
#pragma unroll
        for (int nt = 0; nt < 2; ++nt) {
            const int colg = w * 32 + nt * 16 + cl;
#pragma unroll
            for (int r = 0; r < 4; ++r) {
                const int row = gq * 4 + r;
                hs[row * 128 + (((colg >> 3) ^ (row & 15)) * 8) + (colg & 7)] =
                    (_Float16)fmaxf(hacc[nt][r], 0.f);
            }
        }
        __syncthreads();  // B2: h ready

        // ---- u = relu(h @ hf2^T), cols [w*16, w*16+16)
        f4 uacc = {};
#pragma unroll
        for (int kk = 0; kk < 4; ++kk) {
            h8 a = *(const h8*)&hs[cl * 128 + (((kk * 4 + gq) ^ (cl & 15)) * 8)];
            uacc = MFMA16(a, hf2f[kk], uacc);
        }
        {
            const int colg = w * 16 + cl;
#pragma unroll
            for (int r = 0; r < 4; ++r) {
                const int row = gq * 4 + r;
                us[row * 64 + (((colg >> 3) ^ (row & 7)) * 8) + (colg & 7)] =
                    (_Float16)fmaxf(uacc[r], 0.f);
            }
        }
        __syncthreads();  // B3: u ready

        // ---- x_new = u@Bw^T + D@Ew^T + x@W_eff (one fused accumulator)
        f4 acc[2] = {};
#pragma unroll
        for (int kk = 0; kk < 2; ++kk) {
            h8 a = *(const h8*)&us[cl * 64 + (((kk * 4 + gq) ^ (cl & 7)) * 8)];
            acc[0] = MFMA16(a, bwf[0][kk], acc[0]);
            acc[1] = MFMA16(a, bwf[1][kk], acc[1]);
        }
        {
            h8 a = *(const h8*)&dts[cl * 32 + ((gq ^ (cl & 3)) * 8)];
            acc[0] = MFMA16(a, ewf[0], acc[0]);
            acc[1] = MFMA16(a, ewf[1], acc[1]);
        }
#pragma unroll
        for (int kk = 0; kk < 4; ++kk) {
            h8 a = *(const h8*)&xs[cur][cl * 128 + (((kk * 4 + gq) ^ (cl & 15)) * 8)];
            acc[0] = MFMA16(a, wtf[0][kk], acc[0]);
            acc[1] = MFMA16(a, wtf[1][kk], acc[1]);
        }

        // ---- writes
        const int nxt = cur ^ 1;
        if constexpr (FINAL) {
            const size_t t = (size_t)c * LCH + k;
#pragma unroll
            for (int nt = 0; nt < 2; ++nt) {
                const int colg = w * 32 + nt * 16 + cl;
#pragma unroll
                for (int r = 0; r < 4; ++r) {
                    const int row = gq * 4 + r;
                    const float v = acc[nt][r];
                    Xout[(t * BS + b0 + row) * 128 + colg] = v;
                    xs[nxt][row * 128 + (((colg >> 3) ^ (row & 15)) * 8) + (colg & 7)] =
                        (_Float16)v;
                }
            }
            if (w == 3 && cl == 15) {  // colg(nt=1) == 127
#pragma unroll
                for (int r = 0; r < 4; ++r)
                    Yout[t * BS + b0 + gq * 4 + r] = acc[1][r];
            }
        } else {
            if (k == LCH - 1) {
#pragma unroll
                for (int nt = 0; nt < 2; ++nt) {
                    const int colg = w * 32 + nt * 16 + cl;
#pragma unroll
                    for (int r = 0; r < 4; ++r) {
                        const int row = gq * 4 + r;
                        Fbuf[((size_t)c * BS + b0 + row) * 128 + colg] = acc[nt][r];
                    }
                }
            } else {
#pragma unroll
                for (int nt = 0; nt < 2; ++nt) {
                    const int colg = w * 32 + nt * 16 + cl;
#pragma unroll
                    for (int r = 0; r < 4; ++r) {
                        const int row = gq * 4 + r;
                        xs[nxt][row * 128 + (((colg >> 3) ^ (row & 15)) * 8) + (colg & 7)] =
                            (_Float16)acc[nt][r];
                    }
                }
            }
        }
        cur = nxt;
    }
}

// ---------------------------------------------------------------------------
// carry propagation: init_0 = x_in; init_c = init_{c-1} @ W^64 + F_{c-1}
// grid 64 (btile), 256 threads
// ---------------------------------------------------------------------------
__global__ __launch_bounds__(256, 2)
void carry_kernel(const float* __restrict__ x_in, char* __restrict__ ws)
{
    const int tid  = threadIdx.x;
    const int lane = tid & 63;
    const int w    = tid >> 6;
    const int cl   = lane & 15;
    const int gq   = lane >> 4;
    const int b0   = blockIdx.x * 16;

    const _Float16* WL = (const _Float16*)(ws + WS_WL16);
    const float* Fbuf  = (const float*)(ws + WS_F);
    float* Init        = (float*)(ws + WS_INIT);

    __shared__ __align__(16) _Float16 xs[2][16 * 128];

    h8 wlf[2][4];
#pragma unroll
    for (int nt = 0; nt < 2; ++nt) {
        const int ng = w * 32 + nt * 16 + cl;
#pragma unroll
        for (int kk = 0; kk < 4; ++kk)
            wlf[nt][kk] = *(const h8*)&WL[ng * 128 + kk * 32 + gq * 8];
    }

    {
        const int row = tid >> 4, c8 = tid & 15;
        const float* src = &x_in[(b0 + row) * 128 + c8 * 8];
        f4 v0 = *(const f4*)src, v1 = *(const f4*)(src + 4);
        float* dst = &Init[((size_t)(b0 + row)) * 128 + c8 * 8];
        *(f4*)dst = v0;
        *(f4*)(dst + 4) = v1;
        h8 hv;
#pragma unroll
        for (int j = 0; j < 4; ++j) { hv[j] = (_Float16)v0[j]; hv[4 + j] = (_Float16)v1[j]; }
        *(h8*)&xs[0][row * 128 + ((c8 ^ row) & 15) * 8] = hv;
    }
    __syncthreads();

    int cur = 0;
    for (int cc = 1; cc < NCH; ++cc) {
        f4 acc[2] = {};
#pragma unroll
        for (int kk = 0; kk < 4; ++kk) {
            h8 a = *(const h8*)&xs[cur][cl * 128 + (((kk * 4 + gq) ^ (cl & 15)) * 8)];
            acc[0] = MFMA16(a, wlf[0][kk], acc[0]);
            acc[1] = MFMA16(a, wlf[1][kk], acc[1]);
        }
        const int nxt = cur ^ 1;
#pragma unroll
        for (int nt = 0; nt < 2; ++nt) {
            const int colg = w * 32 + nt * 16 + cl;
#pragma unroll
            for (int r = 0; r < 4; ++r) {
                const int row = gq * 4 + r;
                const float v =
                    acc[nt][r] + Fbuf[((size_t)(cc - 1) * BS + b0 + row) * 128 + colg];
                Init[((size_t)cc * BS + b0 + row) * 128 + colg] = v;
                xs[nxt][row * 128 + (((colg >> 3) ^ (row & 15)) * 8) + (colg & 7)] =
                    (_Float16)v;
            }
        }
        __syncthreads();
        cur = nxt;
    }
}

// ---------------------------------------------------------------------------
extern "C" void kernel_launch(void* const* d_in, const int* in_sizes, int n_in,
                              void* d_out, int out_size, void* d_ws, size_t ws_size,
                              hipStream_t stream)
{
    const float* x_in = (const float*)d_in[0];
    const float* Mfl  = (const float*)d_in[1];
    const float* DTi  = (const float*)d_in[2];
    const float* Din  = (const float*)d_in[3];
    const float* Aw   = (const float*)d_in[4];
    const float* As   = (const float*)d_in[5];
    const float* Bw   = (const float*)d_in[6];
    const float* Ew   = (const float*)d_in[7];
    const float* hf1  = (const float*)d_in[8];
    const float* hf2  = (const float*)d_in[9];
    char* ws   = (char*)d_ws;
    float* Xout = (float*)d_out;
    float* Yout = Xout + XTOT;

    prep_kernel<<<dim3(160), dim3(128), 0, stream>>>(Aw, As, hf1, hf2, Bw, Ew, ws);

    float* A32 = (float*)(ws + WS_W32A);
    float* B32 = (float*)(ws + WS_W32B);
    for (int i = 0; i < 6; ++i) {  // W -> W^64 by repeated squaring; ends in A32
        const float* src = (i & 1) ? B32 : A32;
        float* dst       = (i & 1) ? A32 : B32;
        matsq_kernel<<<dim3(64), dim3(256), 0, stream>>>(src, dst);
    }
    conv_kernel<<<dim3(64), dim3(256), 0, stream>>>(A32, ws);

    // P1: chunk-local scans (chunks 0..14), writes F
    scan_chunk<false><<<dim3(15 * 64), dim3(256), 0, stream>>>(Mfl, DTi, Din, ws, nullptr, nullptr);
    // P2: carry propagation, writes INIT[0..15]
    carry_kernel<<<dim3(64), dim3(256), 0, stream>>>(x_in, ws);
    // P3: true scans, writes X and Y
    scan_chunk<true><<<dim3(16 * 64), dim3(256), 0, stream>>>(Mfl, DTi, Din, ws, Xout, Yout);
}

// Round 2
// 457.539 us; speedup vs baseline: 1.0282x; 1.0282x over previous
//
#include <hip/hip_runtime.h>

typedef _Float16 h4 __attribute__((ext_vector_type(4)));
typedef _Float16 h8 __attribute__((ext_vector_type(8)));
typedef float f4 __attribute__((ext_vector_type(4)));

#define MFMA16(a, b, c) __builtin_amdgcn_mfma_f32_16x16x32_f16((a), (b), (c), 0, 0, 0)

static constexpr int TT  = 1024;
static constexpr int BS  = 1024;
static constexpr int LCH = 64;   // chunk length
static constexpr int NCH = 16;   // number of chunks
static constexpr size_t XTOT = (size_t)TT * BS * 128;

// workspace byte offsets
static constexpr size_t WS_WT16 = 0;       // 128x128 f16 : W_eff^T-layout (= S row-major)
static constexpr size_t WS_HF1  = 32768;   // 128x64  f16
static constexpr size_t WS_HF2  = 49152;   // 64x128  f16
static constexpr size_t WS_BW   = 65536;   // 128x64  f16
static constexpr size_t WS_EW   = 81920;   // 128x32  f16
static constexpr size_t WS_W32A = 122880;  // 128x128 f32 scratch (ends holding W^64)
static constexpr size_t WS_W32B = 188416;  // 128x128 f32 scratch
static constexpr size_t WS_F    = 253952;  // 16*1024*128 f32: chunk-local finals
static constexpr size_t WS_INIT = WS_F + (size_t)NCH * BS * 128 * 4;
static constexpr size_t WS_DRV  = WS_INIT + (size_t)NCH * BS * 128 * 4;
// drive: T*B*128 f16 in fragment order = 268 MB (ws is ~2.1 GB per poison-fill size)

// ---------------------------------------------------------------------------
// prep: W_eff (softmax+scale, stored transposed = S row-major) + weight f16 copies
// ---------------------------------------------------------------------------
__global__ void prep_kernel(const float* __restrict__ Aw, const float* __restrict__ As,
                            const float* __restrict__ hf1, const float* __restrict__ hf2,
                            const float* __restrict__ Bw, const float* __restrict__ Ew,
                            char* __restrict__ ws)
{
    const int tid = threadIdx.x;  // 128
    const int bid = blockIdx.x;   // 160
    if (bid < 128) {
        __shared__ float red[128];
        const int n = bid;
        const float a = Aw[n * 128 + tid];
        red[tid] = a;
        __syncthreads();
        for (int s = 64; s > 0; s >>= 1) {
            if (tid < s) red[tid] = fmaxf(red[tid], red[tid + s]);
            __syncthreads();
        }
        const float mx = red[0];
        __syncthreads();
        const float e = expf(a - mx);
        red[tid] = e;
        __syncthreads();
        for (int s = 64; s > 0; s >>= 1) {
            if (tid < s) red[tid] += red[tid + s];
            __syncthreads();
        }
        const float sm  = e / red[0];
        const float asv = As[n * 128 + tid];
        const float sc  = 1.0f - 0.1f * (1.0f / (1.0f + expf(-asv)));
        const float val = sc * sm;   // S[n][tid]
        ((_Float16*)(ws + WS_WT16))[n * 128 + tid] = (_Float16)val;
        ((float*)(ws + WS_W32A))[n * 128 + tid]    = val;
    } else {
        const int b2 = bid - 128;  // 32 blocks
        for (int i = b2 * 128 + tid; i < 8192; i += 32 * 128) {
            ((_Float16*)(ws + WS_HF1))[i] = (_Float16)hf1[i];
            ((_Float16*)(ws + WS_HF2))[i] = (_Float16)hf2[i];
            ((_Float16*)(ws + WS_BW))[i]  = (_Float16)Bw[i];
            if (i < 4096) ((_Float16*)(ws + WS_EW))[i] = (_Float16)Ew[i];
        }
    }
}

// ---------------------------------------------------------------------------
// transposed-layout matrix square: Tout[n][k] = sum_m Tin[m][k]*Tin[n][m]
// ---------------------------------------------------------------------------
__global__ void matsq_kernel(const float* __restrict__ in, float* __restrict__ out)
{
    const int idx = blockIdx.x * 256 + threadIdx.x;  // 64 blocks
    const int n = idx >> 7, k = idx & 127;
    float acc = 0.f;
    for (int m = 0; m < 128; ++m) acc += in[m * 128 + k] * in[n * 128 + m];
    out[idx] = acc;
}

// ---------------------------------------------------------------------------
// Phase D: drive[t][b][:] = relu(relu(md@hf1^T)@hf2^T)@Bw^T + D@Ew^T
// Block = 4 t-steps x 16 b-rows; drive stored f16 in FRAGMENT ORDER:
// Drv[((t*64 + bt)*256 + tid)*8 + (nt*4 + r)]  (16B/lane coalesced)
// ---------------------------------------------------------------------------
__global__ __launch_bounds__(256, 3)
void drive_kernel(const float* __restrict__ Mfl, const float* __restrict__ DTi,
                  const float* __restrict__ Din, char* __restrict__ ws)
{
    const int tid  = threadIdx.x;
    const int lane = tid & 63;
    const int w    = tid >> 6;
    const int cl   = lane & 15;
    const int gq   = lane >> 4;
    const int bt   = blockIdx.x & 63;
    const int tq   = blockIdx.x >> 6;   // 0..255
    const int b0   = bt * 16;

    const _Float16* Hf1  = (const _Float16*)(ws + WS_HF1);
    const _Float16* Hf2  = (const _Float16*)(ws + WS_HF2);
    const _Float16* Bw16 = (const _Float16*)(ws + WS_BW);
    const _Float16* Ew16 = (const _Float16*)(ws + WS_EW);
    _Float16* Drv        = (_Float16*)(ws + WS_DRV);

    __shared__ __align__(16) _Float16 mds[4][16 * 64];
    __shared__ __align__(16) _Float16 dts[4][16 * 32];
    __shared__ __align__(16) _Float16 hs[4][16 * 128];
    __shared__ __align__(16) _Float16 us[4][16 * 64];

    // weight B-fragments
    h8 hf1f[2][2], bwf[2][2], ewf[2], hf2f[4];
#pragma unroll
    for (int nt = 0; nt < 2; ++nt) {
        const int ng = w * 32 + nt * 16 + cl;
#pragma unroll
        for (int kk = 0; kk < 2; ++kk) {
            hf1f[nt][kk] = *(const h8*)&Hf1[ng * 64 + kk * 32 + gq * 8];
            bwf[nt][kk]  = *(const h8*)&Bw16[ng * 64 + kk * 32 + gq * 8];
        }
        ewf[nt] = *(const h8*)&Ew16[ng * 32 + gq * 8];
    }
    {
        const int ng = w * 16 + cl;
#pragma unroll
        for (int kk = 0; kk < 4; ++kk)
            hf2f[kk] = *(const h8*)&Hf2[ng * 128 + kk * 32 + gq * 8];
    }

    // ---- load 4 steps of inputs (role split: tid<128 -> Mfl+Din, else DTi)
    const int qrow = (tid & 127) >> 3;
    const int qc4  = (tid & 7) * 4;
    f4 pm[4], pd[4];
#pragma unroll
    for (int s = 0; s < 4; ++s) {
        const size_t t  = (size_t)tq * 4 + s;
        const size_t rb = (t * BS + b0 + qrow) * 32 + qc4;
        pm[s] = (tid < 128) ? *(const f4*)&Mfl[rb] : *(const f4*)&DTi[rb];
        if (tid < 128) pd[s] = *(const f4*)&Din[rb];
    }
    // ---- stage
#pragma unroll
    for (int s = 0; s < 4; ++s) {
        const int col = (tid < 128) ? qc4 : (32 + qc4);
        h4 hv;
#pragma unroll
        for (int j = 0; j < 4; ++j) hv[j] = (_Float16)pm[s][j];
        *(h4*)&mds[s][qrow * 64 + (((col >> 3) ^ (qrow & 7)) * 8) + (col & 7)] = hv;
        if (tid < 128) {
            h4 h2;
#pragma unroll
            for (int j = 0; j < 4; ++j) h2[j] = (_Float16)pd[s][j];
            *(h4*)&dts[s][qrow * 32 + (((qc4 >> 3) ^ (qrow & 3)) * 8) + (qc4 & 7)] = h2;
        }
    }
    __syncthreads();

    // ---- GEMM1: h = relu(md @ hf1^T)
#pragma unroll
    for (int s = 0; s < 4; ++s) {
        f4 ha[2] = {};
#pragma unroll
        for (int kk = 0; kk < 2; ++kk) {
            h8 a = *(const h8*)&mds[s][cl * 64 + (((kk * 4 + gq) ^ (cl & 7)) * 8)];
            ha[0] = MFMA16(a, hf1f[0][kk], ha[0]);
            ha[1] = MFMA16(a, hf1f[1][kk], ha[1]);
        }
#pragma unroll
        for (int nt = 0; nt < 2; ++nt) {
            const int colg = w * 32 + nt * 16 + cl;
#pragma unroll
            for (int r = 0; r < 4; ++r) {
                const int row = gq * 4 + r;
                hs[s][row * 128 + (((colg >> 3) ^ (row & 15)) * 8) + (colg & 7)] =
                    (_Float16)fmaxf(ha[nt][r], 0.f);
            }
        }
    }
    __syncthreads();

    // ---- GEMM2: u = relu(h @ hf2^T)
#pragma unroll
    for (int s = 0; s < 4; ++s) {
        f4 ua = {};
#pragma unroll
        for (int kk = 0; kk < 4; ++kk) {
            h8 a = *(const h8*)&hs[s][cl * 128 + (((kk * 4 + gq) ^ (cl & 15)) * 8)];
            ua = MFMA16(a, hf2f[kk], ua);
        }
        const int colg = w * 16 + cl;
#pragma unroll
        for (int r = 0; r < 4; ++r) {
            const int row = gq * 4 + r;
            us[s][row * 64 + (((colg >> 3) ^ (row & 7)) * 8) + (colg & 7)] =
                (_Float16)fmaxf(ua[r], 0.f);
        }
    }
    __syncthreads();

    // ---- GEMM3: drive = u@Bw^T + D@Ew^T  -> store fragment-order f16
#pragma unroll
    for (int s = 0; s < 4; ++s) {
        f4 acc[2] = {};
#pragma unroll
        for (int kk = 0; kk < 2; ++kk) {
            h8 a = *(const h8*)&us[s][cl * 64 + (((kk * 4 + gq) ^ (cl & 7)) * 8)];
            acc[0] = MFMA16(a, bwf[0][kk], acc[0]);
            acc[1] = MFMA16(a, bwf[1][kk], acc[1]);
        }
        {
            h8 a = *(const h8*)&dts[s][cl * 32 + ((gq ^ (cl & 3)) * 8)];
            acc[0] = MFMA16(a, ewf[0], acc[0]);
            acc[1] = MFMA16(a, ewf[1], acc[1]);
        }
        h8 hv;
#pragma unroll
        for (int nt = 0; nt < 2; ++nt)
#pragma unroll
            for (int r = 0; r < 4; ++r) hv[nt * 4 + r] = (_Float16)acc[nt][r];
        const size_t t = (size_t)tq * 4 + s;
        *(h8*)&Drv[((t * 64 + bt) * 256 + tid) * 8] = hv;
    }
}

// ---------------------------------------------------------------------------
// scan: x_{k+1} = x_k @ W_eff + drive (drive from Drv, fragment order).
// FINAL=false: zero init, write F_c at k=63.  FINAL=true: init from INIT,
// write X and Y.  1 barrier per step.
// ---------------------------------------------------------------------------
template <bool FINAL>
__global__ __launch_bounds__(256, 4)
void scan_kernel(char* __restrict__ ws, float* __restrict__ Xout, float* __restrict__ Yout)
{
    const int tid  = threadIdx.x;
    const int lane = tid & 63;
    const int w    = tid >> 6;
    const int cl   = lane & 15;
    const int gq   = lane >> 4;
    const int bt   = blockIdx.x & 63;
    const int c    = blockIdx.x >> 6;
    const int b0   = bt * 16;

    const _Float16* Wt16 = (const _Float16*)(ws + WS_WT16);
    const _Float16* Drv  = (const _Float16*)(ws + WS_DRV);
    float* Fbuf          = (float*)(ws + WS_F);
    const float* Init    = (const float*)(ws + WS_INIT);

    __shared__ __align__(16) _Float16 xs[2][16 * 128];

    h8 wtf[2][4];
#pragma unroll
    for (int nt = 0; nt < 2; ++nt) {
        const int ng = w * 32 + nt * 16 + cl;
#pragma unroll
        for (int kk = 0; kk < 4; ++kk)
            wtf[nt][kk] = *(const h8*)&Wt16[ng * 128 + kk * 32 + gq * 8];
    }

    if constexpr (FINAL) {
        const int row = tid >> 4, c8 = tid & 15;
        const float* src = &Init[((size_t)c * BS + b0 + row) * 128 + c8 * 8];
        f4 v0 = *(const f4*)src;
        f4 v1 = *(const f4*)(src + 4);
        h8 hv;
#pragma unroll
        for (int j = 0; j < 4; ++j) { hv[j] = (_Float16)v0[j]; hv[4 + j] = (_Float16)v1[j]; }
        *(h8*)&xs[0][row * 128 + ((c8 ^ row) & 15) * 8] = hv;
    } else {
        h8 z = {};
        *(h8*)&xs[0][tid * 8] = z;
    }
    __syncthreads();

    const size_t dbase = (((size_t)c * 64) * 64 + bt) * 2048 + (size_t)tid * 8;
    h8 dc = *(const h8*)&Drv[dbase];

    int cur = 0;
    for (int k = 0; k < LCH; ++k) {
        f4 acc[2];
#pragma unroll
        for (int nt = 0; nt < 2; ++nt)
#pragma unroll
            for (int r = 0; r < 4; ++r) acc[nt][r] = (float)dc[nt * 4 + r];

        if (k + 1 < LCH) dc = *(const h8*)&Drv[dbase + (size_t)(k + 1) * 64 * 2048];

#pragma unroll
        for (int kk = 0; kk < 4; ++kk) {
            h8 a = *(const h8*)&xs[cur][cl * 128 + (((kk * 4 + gq) ^ (cl & 15)) * 8)];
            acc[0] = MFMA16(a, wtf[0][kk], acc[0]);
            acc[1] = MFMA16(a, wtf[1][kk], acc[1]);
        }

        const int nxt = cur ^ 1;
        if constexpr (FINAL) {
            const size_t t = (size_t)c * LCH + k;
#pragma unroll
            for (int nt = 0; nt < 2; ++nt) {
                const int colg = w * 32 + nt * 16 + cl;
#pragma unroll
                for (int r = 0; r < 4; ++r) {
                    const int row = gq * 4 + r;
                    const float v = acc[nt][r];
                    Xout[(t * BS + b0 + row) * 128 + colg] = v;
                    xs[nxt][row * 128 + (((colg >> 3) ^ (row & 15)) * 8) + (colg & 7)] =
                        (_Float16)v;
                }
            }
            if (w == 3 && cl == 15) {
#pragma unroll
                for (int r = 0; r < 4; ++r)
                    Yout[t * BS + b0 + gq * 4 + r] = acc[1][r];
            }
        } else {
            if (k == LCH - 1) {
#pragma unroll
                for (int nt = 0; nt < 2; ++nt) {
                    const int colg = w * 32 + nt * 16 + cl;
#pragma unroll
                    for (int r = 0; r < 4; ++r) {
                        const int row = gq * 4 + r;
                        Fbuf[((size_t)c * BS + b0 + row) * 128 + colg] = acc[nt][r];
                    }
                }
            } else {
#pragma unroll
                for (int nt = 0; nt < 2; ++nt) {
                    const int colg = w * 32 + nt * 16 + cl;
#pragma unroll
                    for (int r = 0; r < 4; ++r) {
                        const int row = gq * 4 + r;
                        xs[nxt][row * 128 + (((colg >> 3) ^ (row & 15)) * 8) + (colg & 7)] =
                            (_Float16)acc[nt][r];
                    }
                }
            }
        }
        __syncthreads();
        cur = nxt;
    }
}

// ---------------------------------------------------------------------------
// carry propagation: init_0 = x_in; init_c = init_{c-1} @ W^64 + F_{c-1}
// W^64 read f32 from ws (converted to f16 frags in-register).
// ---------------------------------------------------------------------------
__global__ __launch_bounds__(256, 2)
void carry_kernel(const float* __restrict__ x_in, char* __restrict__ ws)
{
    const int tid  = threadIdx.x;
    const int lane = tid & 63;
    const int w    = tid >> 6;
    const int cl   = lane & 15;
    const int gq   = lane >> 4;
    const int b0   = blockIdx.x * 16;

    const float* WL32 = (const float*)(ws + WS_W32A);
    const float* Fbuf = (const float*)(ws + WS_F);
    float* Init       = (float*)(ws + WS_INIT);

    __shared__ __align__(16) _Float16 xs[2][16 * 128];

    h8 wlf[2][4];
#pragma unroll
    for (int nt = 0; nt < 2; ++nt) {
        const int ng = w * 32 + nt * 16 + cl;
#pragma unroll
        for (int kk = 0; kk < 4; ++kk) {
            f4 a0 = *(const f4*)&WL32[ng * 128 + kk * 32 + gq * 8];
            f4 a1 = *(const f4*)&WL32[ng * 128 + kk * 32 + gq * 8 + 4];
#pragma unroll
            for (int j = 0; j < 4; ++j) {
                wlf[nt][kk][j]     = (_Float16)a0[j];
                wlf[nt][kk][4 + j] = (_Float16)a1[j];
            }
        }
    }

    {
        const int row = tid >> 4, c8 = tid & 15;
        const float* src = &x_in[(b0 + row) * 128 + c8 * 8];
        f4 v0 = *(const f4*)src, v1 = *(const f4*)(src + 4);
        float* dst = &Init[((size_t)(b0 + row)) * 128 + c8 * 8];
        *(f4*)dst = v0;
        *(f4*)(dst + 4) = v1;
        h8 hv;
#pragma unroll
        for (int j = 0; j < 4; ++j) { hv[j] = (_Float16)v0[j]; hv[4 + j] = (_Float16)v1[j]; }
        *(h8*)&xs[0][row * 128 + ((c8 ^ row) & 15) * 8] = hv;
    }
    __syncthreads();

    int cur = 0;
    for (int cc = 1; cc < NCH; ++cc) {
        f4 acc[2] = {};
#pragma unroll
        for (int kk = 0; kk < 4; ++kk) {
            h8 a = *(const h8*)&xs[cur][cl * 128 + (((kk * 4 + gq) ^ (cl & 15)) * 8)];
            acc[0] = MFMA16(a, wlf[0][kk], acc[0]);
            acc[1] = MFMA16(a, wlf[1][kk], acc[1]);
        }
        const int nxt = cur ^ 1;
#pragma unroll
        for (int nt = 0; nt < 2; ++nt) {
            const int colg = w * 32 + nt * 16 + cl;
#pragma unroll
            for (int r = 0; r < 4; ++r) {
                const int row = gq * 4 + r;
                const float v =
                    acc[nt][r] + Fbuf[((size_t)(cc - 1) * BS + b0 + row) * 128 + colg];
                Init[((size_t)cc * BS + b0 + row) * 128 + colg] = v;
                xs[nxt][row * 128 + (((colg >> 3) ^ (row & 15)) * 8) + (colg & 7)] =
                    (_Float16)v;
            }
        }
        __syncthreads();
        cur = nxt;
    }
}

// ---------------------------------------------------------------------------
extern "C" void kernel_launch(void* const* d_in, const int* in_sizes, int n_in,
                              void* d_out, int out_size, void* d_ws, size_t ws_size,
                              hipStream_t stream)
{
    const float* x_in = (const float*)d_in[0];
    const float* Mfl  = (const float*)d_in[1];
    const float* DTi  = (const float*)d_in[2];
    const float* Din  = (const float*)d_in[3];
    const float* Aw   = (const float*)d_in[4];
    const float* As   = (const float*)d_in[5];
    const float* Bw   = (const float*)d_in[6];
    const float* Ew   = (const float*)d_in[7];
    const float* hf1  = (const float*)d_in[8];
    const float* hf2  = (const float*)d_in[9];
    char* ws    = (char*)d_ws;
    float* Xout = (float*)d_out;
    float* Yout = Xout + XTOT;

    prep_kernel<<<dim3(160), dim3(128), 0, stream>>>(Aw, As, hf1, hf2, Bw, Ew, ws);

    float* A32 = (float*)(ws + WS_W32A);
    float* B32 = (float*)(ws + WS_W32B);
    for (int i = 0; i < 6; ++i) {  // W -> W^64 by repeated squaring; ends in A32
        const float* src = (i & 1) ? B32 : A32;
        float* dst       = (i & 1) ? A32 : B32;
        matsq_kernel<<<dim3(64), dim3(256), 0, stream>>>(src, dst);
    }

    // Phase D: all drives as one batched GEMM pass (fragment-order f16 in ws)
    drive_kernel<<<dim3(256 * 64), dim3(256), 0, stream>>>(Mfl, DTi, Din, ws);

    // P1: chunk-local scans (chunks 0..14) -> F
    scan_kernel<false><<<dim3(15 * 64), dim3(256), 0, stream>>>(ws, nullptr, nullptr);
    // P2: carry propagation -> INIT
    carry_kernel<<<dim3(64), dim3(256), 0, stream>>>(x_in, ws);
    // P3: true scans -> X, Y
    scan_kernel<true><<<dim3(16 * 64), dim3(256), 0, stream>>>(ws, Xout, Yout);
}

// Round 3
// 434.978 us; speedup vs baseline: 1.0815x; 1.0519x over previous
//
#include <hip/hip_runtime.h>

typedef _Float16 h4 __attribute__((ext_vector_type(4)));
typedef _Float16 h8 __attribute__((ext_vector_type(8)));
typedef float f4 __attribute__((ext_vector_type(4)));

#define MFMA16(a, b, c) __builtin_amdgcn_mfma_f32_16x16x32_f16((a), (b), (c), 0, 0, 0)

static constexpr int TT  = 1024;
static constexpr int BS  = 1024;
static constexpr int LCH = 64;   // chunk length
static constexpr int NCH = 16;   // number of chunks (8 per half)
static constexpr size_t XTOT = (size_t)TT * BS * 128;

// workspace byte offsets
static constexpr size_t WS_WT16 = 0;       // 128x128 f16 : W_eff^T-layout (S row-major)
static constexpr size_t WS_HF1  = 32768;   // 128x64  f16
static constexpr size_t WS_HF2  = 49152;   // 64x128  f16
static constexpr size_t WS_BW   = 65536;   // 128x64  f16
static constexpr size_t WS_EW   = 81920;   // 128x32  f16
static constexpr size_t WS_W64  = 122880;  // 128x128 f16 : (W^64) same T-layout
static constexpr size_t WS_F    = 253952;  // NCH*BS*128 f32: chunk-local finals
static constexpr size_t WS_INIT = WS_F + (size_t)NCH * BS * 128 * 4;
static constexpr size_t WS_DRV  = WS_INIT + (size_t)NCH * BS * 128 * 4;
// Drv: 512*B*128 f16 (one half) = 134 MB -> fits Infinity Cache (256 MB)

template <typename T>
__device__ inline T ntload(const T* p) { return __builtin_nontemporal_load(p); }

// ---------------------------------------------------------------------------
// prep: W_eff (softmax+scale, stored transposed = S row-major) + f16 weights
// ---------------------------------------------------------------------------
__global__ void prep_kernel(const float* __restrict__ Aw, const float* __restrict__ As,
                            const float* __restrict__ hf1, const float* __restrict__ hf2,
                            const float* __restrict__ Bw, const float* __restrict__ Ew,
                            char* __restrict__ ws)
{
    const int tid = threadIdx.x;  // 128
    const int bid = blockIdx.x;   // 160
    if (bid < 128) {
        __shared__ float red[128];
        const int n = bid;
        const float a = Aw[n * 128 + tid];
        red[tid] = a;
        __syncthreads();
        for (int s = 64; s > 0; s >>= 1) {
            if (tid < s) red[tid] = fmaxf(red[tid], red[tid + s]);
            __syncthreads();
        }
        const float mx = red[0];
        __syncthreads();
        const float e = expf(a - mx);
        red[tid] = e;
        __syncthreads();
        for (int s = 64; s > 0; s >>= 1) {
            if (tid < s) red[tid] += red[tid + s];
            __syncthreads();
        }
        const float sm  = e / red[0];
        const float asv = As[n * 128 + tid];
        const float sc  = 1.0f - 0.1f * (1.0f / (1.0f + expf(-asv)));
        ((_Float16*)(ws + WS_WT16))[n * 128 + tid] = (_Float16)(sc * sm);
    } else {
        const int b2 = bid - 128;  // 32 blocks
        for (int i = b2 * 128 + tid; i < 8192; i += 32 * 128) {
            ((_Float16*)(ws + WS_HF1))[i] = (_Float16)hf1[i];
            ((_Float16*)(ws + WS_HF2))[i] = (_Float16)hf2[i];
            ((_Float16*)(ws + WS_BW))[i]  = (_Float16)Bw[i];
            if (i < 4096) ((_Float16*)(ws + WS_EW))[i] = (_Float16)Ew[i];
        }
    }
}

// ---------------------------------------------------------------------------
// W^64 by 6 in-LDS f16 MFMA squarings (T-layout: T' = T*T row-major GEMM).
// One block, 4 waves; wave w owns cols [w*32, w*32+32).
// ---------------------------------------------------------------------------
__global__ void w64_kernel(char* __restrict__ ws)
{
    const int tid  = threadIdx.x;
    const int lane = tid & 63;
    const int w    = tid >> 6;
    const int cl   = lane & 15;
    const int gq   = lane >> 4;

    __shared__ __align__(16) _Float16 Ta[128 * 128];
    __shared__ __align__(16) _Float16 Tb[128 * 128];

    const _Float16* Wt16 = (const _Float16*)(ws + WS_WT16);
    for (int i = tid; i < 2048; i += 256)
        *(h8*)&Ta[i * 8] = *(const h8*)&Wt16[i * 8];
    __syncthreads();

    for (int s = 0; s < 6; ++s) {
        const _Float16* src = (s & 1) ? Tb : Ta;
        _Float16* dst       = (s & 1) ? Ta : Tb;
        f4 acc[8][2];
#pragma unroll
        for (int mt = 0; mt < 8; ++mt)
#pragma unroll
            for (int nt = 0; nt < 2; ++nt) acc[mt][nt] = f4{};
#pragma unroll
        for (int kk = 0; kk < 4; ++kk) {
            h8 b0, b1;
#pragma unroll
            for (int j = 0; j < 8; ++j) {
                const int kr = kk * 32 + gq * 8 + j;
                b0[j] = src[kr * 128 + w * 32 + cl];
                b1[j] = src[kr * 128 + w * 32 + 16 + cl];
            }
#pragma unroll
            for (int mt = 0; mt < 8; ++mt) {
                h8 a = *(const h8*)&src[(mt * 16 + cl) * 128 + kk * 32 + gq * 8];
                acc[mt][0] = MFMA16(a, b0, acc[mt][0]);
                acc[mt][1] = MFMA16(a, b1, acc[mt][1]);
            }
        }
        __syncthreads();
#pragma unroll
        for (int mt = 0; mt < 8; ++mt)
#pragma unroll
            for (int nt = 0; nt < 2; ++nt)
#pragma unroll
                for (int r = 0; r < 4; ++r)
                    dst[(mt * 16 + gq * 4 + r) * 128 + w * 32 + nt * 16 + cl] =
                        (_Float16)acc[mt][nt][r];
        __syncthreads();
    }
    // after s=5 result is in Ta
    _Float16* W64 = (_Float16*)(ws + WS_W64);
    for (int i = tid; i < 2048; i += 256)
        *(h8*)&W64[i * 8] = *(const h8*)&Ta[i * 8];
}

// ---------------------------------------------------------------------------
// Phase D (per half): drive = relu(relu(md@hf1^T)@hf2^T)@Bw^T + D@Ew^T
// Block = 4 t-steps x 16 b-rows; Drv stored f16 in FRAGMENT ORDER:
// Drv[((tl*64 + bt)*256 + tid)*8 + (nt*4 + r)], tl = t - t0.
// ---------------------------------------------------------------------------
__global__ __launch_bounds__(256, 4)
void drive_kernel(const float* __restrict__ Mfl, const float* __restrict__ DTi,
                  const float* __restrict__ Din, char* __restrict__ ws, int t0)
{
    const int tid  = threadIdx.x;
    const int lane = tid & 63;
    const int w    = tid >> 6;
    const int cl   = lane & 15;
    const int gq   = lane >> 4;
    const int bt   = blockIdx.x & 63;
    const int tq   = blockIdx.x >> 6;   // 0..127
    const int b0   = bt * 16;

    const _Float16* Hf1  = (const _Float16*)(ws + WS_HF1);
    const _Float16* Hf2  = (const _Float16*)(ws + WS_HF2);
    const _Float16* Bw16 = (const _Float16*)(ws + WS_BW);
    const _Float16* Ew16 = (const _Float16*)(ws + WS_EW);
    _Float16* Drv        = (_Float16*)(ws + WS_DRV);

    __shared__ __align__(16) _Float16 mds[4][16 * 64];
    __shared__ __align__(16) _Float16 dts[4][16 * 32];
    __shared__ __align__(16) _Float16 hs[4][16 * 128];
    __shared__ __align__(16) _Float16 us[4][16 * 64];

    // ---- load 4 steps of inputs (non-temporal; role split)
    const int qrow = (tid & 127) >> 3;
    const int qc4  = (tid & 7) * 4;
    f4 pm[4], pd[4];
#pragma unroll
    for (int s = 0; s < 4; ++s) {
        const size_t t  = (size_t)(t0 + tq * 4 + s);
        const size_t rb = (t * BS + b0 + qrow) * 32 + qc4;
        pm[s] = (tid < 128) ? ntload((const f4*)&Mfl[rb]) : ntload((const f4*)&DTi[rb]);
        if (tid < 128) pd[s] = ntload((const f4*)&Din[rb]);
    }
    // ---- stage to LDS (f16, swizzled)
#pragma unroll
    for (int s = 0; s < 4; ++s) {
        const int col = (tid < 128) ? qc4 : (32 + qc4);
        h4 hv;
#pragma unroll
        for (int j = 0; j < 4; ++j) hv[j] = (_Float16)pm[s][j];
        *(h4*)&mds[s][qrow * 64 + (((col >> 3) ^ (qrow & 7)) * 8) + (col & 7)] = hv;
        if (tid < 128) {
            h4 h2;
#pragma unroll
            for (int j = 0; j < 4; ++j) h2[j] = (_Float16)pd[s][j];
            *(h4*)&dts[s][qrow * 32 + (((qc4 >> 3) ^ (qrow & 3)) * 8) + (qc4 & 7)] = h2;
        }
    }

    // ---- weight B-fragments (loaded after staging to cut peak VGPR pressure)
    h8 hf1f[2][2], bwf[2][2], ewf[2], hf2f[4];
#pragma unroll
    for (int nt = 0; nt < 2; ++nt) {
        const int ng = w * 32 + nt * 16 + cl;
#pragma unroll
        for (int kk = 0; kk < 2; ++kk) {
            hf1f[nt][kk] = *(const h8*)&Hf1[ng * 64 + kk * 32 + gq * 8];
            bwf[nt][kk]  = *(const h8*)&Bw16[ng * 64 + kk * 32 + gq * 8];
        }
        ewf[nt] = *(const h8*)&Ew16[ng * 32 + gq * 8];
    }
    {
        const int ng = w * 16 + cl;
#pragma unroll
        for (int kk = 0; kk < 4; ++kk)
            hf2f[kk] = *(const h8*)&Hf2[ng * 128 + kk * 32 + gq * 8];
    }
    __syncthreads();

    // ---- GEMM1: h = relu(md @ hf1^T)
#pragma unroll
    for (int s = 0; s < 4; ++s) {
        f4 ha[2] = {};
#pragma unroll
        for (int kk = 0; kk < 2; ++kk) {
            h8 a = *(const h8*)&mds[s][cl * 64 + (((kk * 4 + gq) ^ (cl & 7)) * 8)];
            ha[0] = MFMA16(a, hf1f[0][kk], ha[0]);
            ha[1] = MFMA16(a, hf1f[1][kk], ha[1]);
        }
#pragma unroll
        for (int nt = 0; nt < 2; ++nt) {
            const int colg = w * 32 + nt * 16 + cl;
#pragma unroll
            for (int r = 0; r < 4; ++r) {
                const int row = gq * 4 + r;
                hs[s][row * 128 + (((colg >> 3) ^ (row & 15)) * 8) + (colg & 7)] =
                    (_Float16)fmaxf(ha[nt][r], 0.f);
            }
        }
    }
    __syncthreads();

    // ---- GEMM2: u = relu(h @ hf2^T)
#pragma unroll
    for (int s = 0; s < 4; ++s) {
        f4 ua = {};
#pragma unroll
        for (int kk = 0; kk < 4; ++kk) {
            h8 a = *(const h8*)&hs[s][cl * 128 + (((kk * 4 + gq) ^ (cl & 15)) * 8)];
            ua = MFMA16(a, hf2f[kk], ua);
        }
        const int colg = w * 16 + cl;
#pragma unroll
        for (int r = 0; r < 4; ++r) {
            const int row = gq * 4 + r;
            us[s][row * 64 + (((colg >> 3) ^ (row & 7)) * 8) + (colg & 7)] =
                (_Float16)fmaxf(ua[r], 0.f);
        }
    }
    __syncthreads();

    // ---- GEMM3: drive = u@Bw^T + D@Ew^T  -> fragment-order f16 (cached: re-read)
#pragma unroll
    for (int s = 0; s < 4; ++s) {
        f4 acc[2] = {};
#pragma unroll
        for (int kk = 0; kk < 2; ++kk) {
            h8 a = *(const h8*)&us[s][cl * 64 + (((kk * 4 + gq) ^ (cl & 7)) * 8)];
            acc[0] = MFMA16(a, bwf[0][kk], acc[0]);
            acc[1] = MFMA16(a, bwf[1][kk], acc[1]);
        }
        {
            h8 a = *(const h8*)&dts[s][cl * 32 + ((gq ^ (cl & 3)) * 8)];
            acc[0] = MFMA16(a, ewf[0], acc[0]);
            acc[1] = MFMA16(a, ewf[1], acc[1]);
        }
        h8 hv;
#pragma unroll
        for (int nt = 0; nt < 2; ++nt)
#pragma unroll
            for (int r = 0; r < 4; ++r) hv[nt * 4 + r] = (_Float16)acc[nt][r];
        const size_t tl = (size_t)tq * 4 + s;
        *(h8*)&Drv[((tl * 64 + bt) * 256 + tid) * 8] = hv;
    }
}

// ---------------------------------------------------------------------------
// scan (per half): x_{k+1} = x_k @ W_eff + drive.  Chunks [c0, c0+grid/64).
// FINAL=false: zero init, write F_c.  FINAL=true: init from INIT, write X,Y
// (non-temporal).  Drv prefetch depth 2.
// ---------------------------------------------------------------------------
template <bool FINAL>
__global__ __launch_bounds__(256, 4)
void scan_kernel(char* __restrict__ ws, int c0, float* __restrict__ Xout,
                 float* __restrict__ Yout)
{
    const int tid  = threadIdx.x;
    const int lane = tid & 63;
    const int w    = tid >> 6;
    const int cl   = lane & 15;
    const int gq   = lane >> 4;
    const int bt   = blockIdx.x & 63;
    const int cg   = c0 + (blockIdx.x >> 6);  // global chunk
    const int cloc = cg & 7;                  // chunk within half
    const int b0   = bt * 16;

    const _Float16* Wt16 = (const _Float16*)(ws + WS_WT16);
    const _Float16* Drv  = (const _Float16*)(ws + WS_DRV);
    float* Fbuf          = (float*)(ws + WS_F);
    const float* Init    = (const float*)(ws + WS_INIT);

    __shared__ __align__(16) _Float16 xs[2][16 * 128];

    h8 wtf[2][4];
#pragma unroll
    for (int nt = 0; nt < 2; ++nt) {
        const int ng = w * 32 + nt * 16 + cl;
#pragma unroll
        for (int kk = 0; kk < 4; ++kk)
            wtf[nt][kk] = *(const h8*)&Wt16[ng * 128 + kk * 32 + gq * 8];
    }

    if constexpr (FINAL) {
        const int row = tid >> 4, c8 = tid & 15;
        const float* src = &Init[((size_t)cg * BS + b0 + row) * 128 + c8 * 8];
        f4 v0 = *(const f4*)src;
        f4 v1 = *(const f4*)(src + 4);
        h8 hv;
#pragma unroll
        for (int j = 0; j < 4; ++j) { hv[j] = (_Float16)v0[j]; hv[4 + j] = (_Float16)v1[j]; }
        *(h8*)&xs[0][row * 128 + ((c8 ^ row) & 15) * 8] = hv;
    } else {
        h8 z = {};
        *(h8*)&xs[0][tid * 8] = z;
    }
    __syncthreads();

    const size_t doff = (size_t)cloc * 64 * 131072 + (size_t)bt * 2048 + (size_t)tid * 8;
    auto LD = [&](int k) -> h8 { return *(const h8*)&Drv[doff + (size_t)k * 131072]; };

    int cur = 0;
    auto step = [&](int k, const h8& dc) {
        f4 acc[2];
#pragma unroll
        for (int nt = 0; nt < 2; ++nt)
#pragma unroll
            for (int r = 0; r < 4; ++r) acc[nt][r] = (float)dc[nt * 4 + r];

#pragma unroll
        for (int kk = 0; kk < 4; ++kk) {
            h8 a = *(const h8*)&xs[cur][cl * 128 + (((kk * 4 + gq) ^ (cl & 15)) * 8)];
            acc[0] = MFMA16(a, wtf[0][kk], acc[0]);
            acc[1] = MFMA16(a, wtf[1][kk], acc[1]);
        }

        const int nxt = cur ^ 1;
        if constexpr (FINAL) {
            const size_t t = (size_t)cg * LCH + k;
#pragma unroll
            for (int nt = 0; nt < 2; ++nt) {
                const int colg = w * 32 + nt * 16 + cl;
#pragma unroll
                for (int r = 0; r < 4; ++r) {
                    const int row = gq * 4 + r;
                    const float v = acc[nt][r];
                    __builtin_nontemporal_store(v, &Xout[(t * BS + b0 + row) * 128 + colg]);
                    xs[nxt][row * 128 + (((colg >> 3) ^ (row & 15)) * 8) + (colg & 7)] =
                        (_Float16)v;
                }
            }
            if (w == 3 && cl == 15) {
#pragma unroll
                for (int r = 0; r < 4; ++r)
                    __builtin_nontemporal_store(acc[1][r], &Yout[t * BS + b0 + gq * 4 + r]);
            }
        } else {
            if (k == LCH - 1) {
#pragma unroll
                for (int nt = 0; nt < 2; ++nt) {
                    const int colg = w * 32 + nt * 16 + cl;
#pragma unroll
                    for (int r = 0; r < 4; ++r) {
                        const int row = gq * 4 + r;
                        Fbuf[((size_t)cg * BS + b0 + row) * 128 + colg] = acc[nt][r];
                    }
                }
            } else {
#pragma unroll
                for (int nt = 0; nt < 2; ++nt) {
                    const int colg = w * 32 + nt * 16 + cl;
#pragma unroll
                    for (int r = 0; r < 4; ++r) {
                        const int row = gq * 4 + r;
                        xs[nxt][row * 128 + (((colg >> 3) ^ (row & 15)) * 8) + (colg & 7)] =
                            (_Float16)acc[nt][r];
                    }
                }
            }
        }
        __syncthreads();
        cur = nxt;
    };

    h8 dc0 = LD(0);
    h8 dc1 = LD(1);
    for (int k = 0; k < LCH; k += 2) {
        {
            h8 d = dc0;
            if (k + 2 < LCH) dc0 = LD(k + 2);
            step(k, d);
        }
        {
            h8 d = dc1;
            if (k + 3 < LCH) dc1 = LD(k + 3);
            step(k + 1, d);
        }
    }
}

// ---------------------------------------------------------------------------
// carry: Init[cc] = Init[cc-1] @ W^64 + F[cc-1] for cc in (cc_lo, cc_hi].
// x0 = state before chunk cc_lo ([B][128] f32). copy0: also write Init[cc_lo].
// ---------------------------------------------------------------------------
__global__ __launch_bounds__(256, 2)
void carry_kernel(const float* __restrict__ x0, char* __restrict__ ws,
                  int cc_lo, int cc_hi, int copy0)
{
    const int tid  = threadIdx.x;
    const int lane = tid & 63;
    const int w    = tid >> 6;
    const int cl   = lane & 15;
    const int gq   = lane >> 4;
    const int b0   = blockIdx.x * 16;

    const _Float16* W64 = (const _Float16*)(ws + WS_W64);
    const float* Fbuf   = (const float*)(ws + WS_F);
    float* Init         = (float*)(ws + WS_INIT);

    __shared__ __align__(16) _Float16 xs[2][16 * 128];

    h8 wlf[2][4];
#pragma unroll
    for (int nt = 0; nt < 2; ++nt) {
        const int ng = w * 32 + nt * 16 + cl;
#pragma unroll
        for (int kk = 0; kk < 4; ++kk)
            wlf[nt][kk] = *(const h8*)&W64[ng * 128 + kk * 32 + gq * 8];
    }

    {
        const int row = tid >> 4, c8 = tid & 15;
        const float* src = &x0[(b0 + row) * 128 + c8 * 8];
        f4 v0 = *(const f4*)src, v1 = *(const f4*)(src + 4);
        if (copy0) {
            float* dst = &Init[((size_t)cc_lo * BS + b0 + row) * 128 + c8 * 8];
            *(f4*)dst = v0;
            *(f4*)(dst + 4) = v1;
        }
        h8 hv;
#pragma unroll
        for (int j = 0; j < 4; ++j) { hv[j] = (_Float16)v0[j]; hv[4 + j] = (_Float16)v1[j]; }
        *(h8*)&xs[0][row * 128 + ((c8 ^ row) & 15) * 8] = hv;
    }
    __syncthreads();

    int cur = 0;
    for (int cc = cc_lo + 1; cc <= cc_hi; ++cc) {
        f4 acc[2] = {};
#pragma unroll
        for (int kk = 0; kk < 4; ++kk) {
            h8 a = *(const h8*)&xs[cur][cl * 128 + (((kk * 4 + gq) ^ (cl & 15)) * 8)];
            acc[0] = MFMA16(a, wlf[0][kk], acc[0]);
            acc[1] = MFMA16(a, wlf[1][kk], acc[1]);
        }
        const int nxt = cur ^ 1;
#pragma unroll
        for (int nt = 0; nt < 2; ++nt) {
            const int colg = w * 32 + nt * 16 + cl;
#pragma unroll
            for (int r = 0; r < 4; ++r) {
                const int row = gq * 4 + r;
                const float v =
                    acc[nt][r] + Fbuf[((size_t)(cc - 1) * BS + b0 + row) * 128 + colg];
                Init[((size_t)cc * BS + b0 + row) * 128 + colg] = v;
                xs[nxt][row * 128 + (((colg >> 3) ^ (row & 15)) * 8) + (colg & 7)] =
                    (_Float16)v;
            }
        }
        __syncthreads();
        cur = nxt;
    }
}

// ---------------------------------------------------------------------------
extern "C" void kernel_launch(void* const* d_in, const int* in_sizes, int n_in,
                              void* d_out, int out_size, void* d_ws, size_t ws_size,
                              hipStream_t stream)
{
    const float* x_in = (const float*)d_in[0];
    const float* Mfl  = (const float*)d_in[1];
    const float* DTi  = (const float*)d_in[2];
    const float* Din  = (const float*)d_in[3];
    const float* Aw   = (const float*)d_in[4];
    const float* As   = (const float*)d_in[5];
    const float* Bw   = (const float*)d_in[6];
    const float* Ew   = (const float*)d_in[7];
    const float* hf1  = (const float*)d_in[8];
    const float* hf2  = (const float*)d_in[9];
    char* ws    = (char*)d_ws;
    float* Xout = (float*)d_out;
    float* Yout = Xout + XTOT;
    const float* Init8 = (const float*)(ws + WS_INIT) + (size_t)8 * BS * 128;

    prep_kernel<<<dim3(160), dim3(128), 0, stream>>>(Aw, As, hf1, hf2, Bw, Ew, ws);
    w64_kernel<<<dim3(1), dim3(256), 0, stream>>>(ws);

    // ---- half 1: chunks 0..7 (t 0..511)
    drive_kernel<<<dim3(128 * 64), dim3(256), 0, stream>>>(Mfl, DTi, Din, ws, 0);
    scan_kernel<false><<<dim3(8 * 64), dim3(256), 0, stream>>>(ws, 0, nullptr, nullptr);
    carry_kernel<<<dim3(64), dim3(256), 0, stream>>>(x_in, ws, 0, 8, 1);
    scan_kernel<true><<<dim3(8 * 64), dim3(256), 0, stream>>>(ws, 0, Xout, Yout);

    // ---- half 2: chunks 8..15 (t 512..1023)
    drive_kernel<<<dim3(128 * 64), dim3(256), 0, stream>>>(Mfl, DTi, Din, ws, 512);
    scan_kernel<false><<<dim3(7 * 64), dim3(256), 0, stream>>>(ws, 8, nullptr, nullptr);
    carry_kernel<<<dim3(64), dim3(256), 0, stream>>>(Init8, ws, 8, 15, 0);
    scan_kernel<true><<<dim3(8 * 64), dim3(256), 0, stream>>>(ws, 8, Xout, Yout);
}